// Round 2
// baseline (80.713 us; speedup 1.0000x reference)
//
#include <hip/hip_runtime.h>

// FlexPool BFP quantize: NCHW (64,256,56,56) fp32.
// Per (n,h,w): E = floor(log2(max_c |x|)), ulp = 2^(E-2) (mantissa_bits=3),
// q = clip(rint(x/ulp), -7, 7) * ulp; 0 if the channel block is all-zero.

#define N_  64
#define C_  256
#define HW_ 3136          // 56*56
#define TILE_ 32          // hw positions per block
#define TILES_PER_N (HW_ / TILE_)   // 98

__global__ __launch_bounds__(256)
void bfp_quant_kernel(const float* __restrict__ in, float* __restrict__ out) {
    const int b    = blockIdx.x;
    const int n    = b / TILES_PER_N;
    const int tile = b - n * TILES_PER_N;
    const int base = n * (C_ * HW_) + tile * TILE_;

    const int t    = threadIdx.x;
    const int q    = t & 7;      // float4 slot -> hw offsets q*4 .. q*4+3
    const int crow = t >> 3;     // 0..31: channel row within each group of 32

    __shared__ float pm[32][TILE_];   // [crow][hw] partial absmax
    __shared__ float s_ulp[TILE_];
    __shared__ float s_rcp[TILE_];

    // ---- load all 256 channels for my 4 hw positions into registers ----
    float4 v[8];
    #pragma unroll
    for (int it = 0; it < 8; ++it) {
        const int c = it * 32 + crow;
        v[it] = *reinterpret_cast<const float4*>(in + base + c * HW_ + q * 4);
    }

    // ---- per-thread partial absmax over my 8 channel rows ----
    float m0 = 0.f, m1 = 0.f, m2 = 0.f, m3 = 0.f;
    #pragma unroll
    for (int it = 0; it < 8; ++it) {
        m0 = fmaxf(m0, fabsf(v[it].x));
        m1 = fmaxf(m1, fabsf(v[it].y));
        m2 = fmaxf(m2, fabsf(v[it].z));
        m3 = fmaxf(m3, fabsf(v[it].w));
    }
    *reinterpret_cast<float4*>(&pm[crow][q * 4]) = make_float4(m0, m1, m2, m3);
    __syncthreads();

    // ---- finalize absmax + power-of-two scales per hw position (bitwise) ----
    if (t < TILE_) {
        float amax = 0.f;
        #pragma unroll
        for (int r = 0; r < 32; ++r) amax = fmaxf(amax, pm[r][t]);
        float ulp = 0.f, rcp = 0.f;
        if (amax > 0.f) {
            const unsigned bits = __float_as_uint(amax);
            const int be = (int)(bits >> 23);          // biased exponent (sign=0)
            if (be >= 3) {
                // E = be-127; ulp = 2^(E-2): biased exp = be-2; rcp = 2^(2-E): biased = 256-be
                ulp = __uint_as_float((unsigned)(be - 2) << 23);
                rcp = __uint_as_float((unsigned)(256 - be) << 23);
            } else {
                // denormal / ultra-tiny amax: normalize by 2^64 (never hit by N(0,1) data)
                const unsigned b2 = __float_as_uint(amax * 0x1.0p+64f);
                const int E = (int)(b2 >> 23) - 127 - 64;
                ulp = exp2f((float)(E - 2));
                rcp = exp2f((float)(2 - E));
            }
        }
        s_ulp[t] = ulp;   // amax==0 -> ulp=rcp=0 -> output 0
        s_rcp[t] = rcp;
    }
    __syncthreads();

    const float u0 = s_ulp[q * 4 + 0], r0 = s_rcp[q * 4 + 0];
    const float u1 = s_ulp[q * 4 + 1], r1 = s_rcp[q * 4 + 1];
    const float u2 = s_ulp[q * 4 + 2], r2 = s_rcp[q * 4 + 2];
    const float u3 = s_ulp[q * 4 + 3], r3 = s_rcp[q * 4 + 3];

    // ---- quantize from registers, coalesced store ----
    #pragma unroll
    for (int it = 0; it < 8; ++it) {
        const int c = it * 32 + crow;
        float4 o;
        o.x = fminf(fmaxf(rintf(v[it].x * r0), -7.f), 7.f) * u0;
        o.y = fminf(fmaxf(rintf(v[it].y * r1), -7.f), 7.f) * u1;
        o.z = fminf(fmaxf(rintf(v[it].z * r2), -7.f), 7.f) * u2;
        o.w = fminf(fmaxf(rintf(v[it].w * r3), -7.f), 7.f) * u3;
        *reinterpret_cast<float4*>(out + base + c * HW_ + q * 4) = o;
    }
}

extern "C" void kernel_launch(void* const* d_in, const int* in_sizes, int n_in,
                              void* d_out, int out_size, void* d_ws, size_t ws_size,
                              hipStream_t stream) {
    const float* in = (const float*)d_in[0];
    float* out = (float*)d_out;
    const int grid = N_ * TILES_PER_N;   // 64*98 = 6272 blocks
    bfp_quant_kernel<<<grid, 256, 0, stream>>>(in, out);
}

// Round 4
// 73.971 us; speedup vs baseline: 1.0911x; 1.0911x over previous
//
#include <hip/hip_runtime.h>

// FlexPool BFP quantize: NCHW (64,256,56,56) fp32.
// Per (n,h,w): E = floor(log2(max_c |x|)), ulp = 2^(E-2) (mantissa_bits=3),
// q = clip(rint(x/ulp), -7, 7) * ulp; 0 if the channel block is all-zero.
//
// Streaming kernel: read-once + write-once, 411 MB total -> nontemporal
// loads/stores (native ext_vector float4 so the builtin accepts them).
// Absmax reduced per-wave via shuffles, single __syncthreads for the
// 4-wave combine (512 B LDS).

#define N_  64
#define C_  256
#define HW_ 3136          // 56*56
#define TILE_ 32          // hw positions per block (= 128 B per channel row)
#define TILES_PER_N (HW_ / TILE_)   // 98

typedef float f4 __attribute__((ext_vector_type(4)));

__device__ __forceinline__ void po2_scales(float amax, float& u, float& r) {
    // u = 2^(E-2), r = 2^(2-E) with E = floor(log2(amax)); 0 if amax == 0.
    u = 0.f; r = 0.f;
    if (amax > 0.f) {
        const int be = (int)(__float_as_uint(amax) >> 23);   // biased exponent
        if (be >= 3) {
            u = __uint_as_float((unsigned)(be - 2) << 23);
            r = __uint_as_float((unsigned)(256 - be) << 23);
        } else {
            // denormal / ultra-tiny amax (unreachable for N(0,1) data)
            const unsigned b2 = __float_as_uint(amax * 0x1.0p+64f);
            const int E = (int)(b2 >> 23) - 191;             // -127 - 64
            u = exp2f((float)(E - 2));
            r = exp2f((float)(2 - E));
        }
    }
}

__global__ __launch_bounds__(256)
void bfp_quant_kernel(const float* __restrict__ in, float* __restrict__ out) {
    const int b    = blockIdx.x;
    const int n    = b / TILES_PER_N;
    const int tile = b - n * TILES_PER_N;
    const int base = n * (C_ * HW_) + tile * TILE_;

    const int t    = threadIdx.x;
    const int q    = t & 7;      // float4 slot -> hw offsets q*4 .. q*4+3
    const int crow = t >> 3;     // 0..31: channel row within each group of 32
    const int w    = t >> 6;     // wave id 0..3

    __shared__ f4 pw[4][8];      // per-wave, per-q partial absmax

    // ---- nontemporal load: all 256 channels for my 4 hw positions ----
    const float* p = in + base + crow * HW_ + q * 4;
    f4 v[8];
    #pragma unroll
    for (int it = 0; it < 8; ++it)
        v[it] = __builtin_nontemporal_load(
                    reinterpret_cast<const f4*>(p + it * (32 * HW_)));

    // ---- per-thread partial absmax over my 8 channel rows ----
    float m0 = 0.f, m1 = 0.f, m2 = 0.f, m3 = 0.f;
    #pragma unroll
    for (int it = 0; it < 8; ++it) {
        m0 = fmaxf(m0, fabsf(v[it].x));
        m1 = fmaxf(m1, fabsf(v[it].y));
        m2 = fmaxf(m2, fabsf(v[it].z));
        m3 = fmaxf(m3, fabsf(v[it].w));
    }

    // ---- wave-internal reduce across the 8 lanes sharing this q (bits 3..5) ----
    #pragma unroll
    for (int mask = 8; mask <= 32; mask <<= 1) {
        m0 = fmaxf(m0, __shfl_xor(m0, mask, 64));
        m1 = fmaxf(m1, __shfl_xor(m1, mask, 64));
        m2 = fmaxf(m2, __shfl_xor(m2, mask, 64));
        m3 = fmaxf(m3, __shfl_xor(m3, mask, 64));
    }
    if ((crow & 7) == 0) {
        f4 pv; pv.x = m0; pv.y = m1; pv.z = m2; pv.w = m3;
        pw[w][q] = pv;
    }
    __syncthreads();

    // ---- combine the 4 wave partials (broadcast LDS reads) ----
    const f4 a0 = pw[0][q], a1 = pw[1][q], a2 = pw[2][q], a3 = pw[3][q];
    const float amx = fmaxf(fmaxf(a0.x, a1.x), fmaxf(a2.x, a3.x));
    const float amy = fmaxf(fmaxf(a0.y, a1.y), fmaxf(a2.y, a3.y));
    const float amz = fmaxf(fmaxf(a0.z, a1.z), fmaxf(a2.z, a3.z));
    const float amw = fmaxf(fmaxf(a0.w, a1.w), fmaxf(a2.w, a3.w));

    float u0, r0, u1, r1, u2, r2, u3, r3;
    po2_scales(amx, u0, r0);
    po2_scales(amy, u1, r1);
    po2_scales(amz, u2, r2);
    po2_scales(amw, u3, r3);

    // ---- quantize from registers, nontemporal coalesced store ----
    float* po = out + base + crow * HW_ + q * 4;
    #pragma unroll
    for (int it = 0; it < 8; ++it) {
        f4 o;
        o.x = fminf(fmaxf(rintf(v[it].x * r0), -7.f), 7.f) * u0;
        o.y = fminf(fmaxf(rintf(v[it].y * r1), -7.f), 7.f) * u1;
        o.z = fminf(fmaxf(rintf(v[it].z * r2), -7.f), 7.f) * u2;
        o.w = fminf(fmaxf(rintf(v[it].w * r3), -7.f), 7.f) * u3;
        __builtin_nontemporal_store(o,
            reinterpret_cast<f4*>(po + it * (32 * HW_)));
    }
}

extern "C" void kernel_launch(void* const* d_in, const int* in_sizes, int n_in,
                              void* d_out, int out_size, void* d_ws, size_t ws_size,
                              hipStream_t stream) {
    const float* in = (const float*)d_in[0];
    float* out = (float*)d_out;
    const int grid = N_ * TILES_PER_N;   // 64*98 = 6272 blocks
    bfp_quant_kernel<<<grid, 256, 0, stream>>>(in, out);
}

// Round 5
// 72.453 us; speedup vs baseline: 1.1140x; 1.0209x over previous
//
#include <hip/hip_runtime.h>

// FlexPool BFP quantize: NCHW (64,256,56,56) fp32.
// Per (n,h,w): E = floor(log2(max_c |x|)), ulp = 2^(E-2) (mantissa_bits=3),
// q = clip(rint(x/ulp), -7, 7) * ulp; 0 if the channel block is all-zero.
//
// Streaming, read-once/write-once, nontemporal. Tile = 64 hw positions so
// each wave-level load instruction covers 4 contiguous 256 B segments
// (vs 8x128 B before) for better DRAM page locality.

#define N_  64
#define C_  256
#define HW_ 3136          // 56*56
#define TILE_ 64          // hw positions per block (= 256 B per channel row)
#define TILES_PER_N (HW_ / TILE_)   // 49

typedef float f4 __attribute__((ext_vector_type(4)));

__device__ __forceinline__ void po2_scales(float amax, float& u, float& r) {
    // u = 2^(E-2), r = 2^(2-E) with E = floor(log2(amax)); 0 if amax == 0.
    u = 0.f; r = 0.f;
    if (amax > 0.f) {
        const int be = (int)(__float_as_uint(amax) >> 23);   // biased exponent
        if (be >= 3) {
            u = __uint_as_float((unsigned)(be - 2) << 23);
            r = __uint_as_float((unsigned)(256 - be) << 23);
        } else {
            // denormal / ultra-tiny amax (unreachable for N(0,1) data)
            const unsigned b2 = __float_as_uint(amax * 0x1.0p+64f);
            const int E = (int)(b2 >> 23) - 191;             // -127 - 64
            u = exp2f((float)(E - 2));
            r = exp2f((float)(2 - E));
        }
    }
}

__global__ __launch_bounds__(256)
void bfp_quant_kernel(const float* __restrict__ in, float* __restrict__ out) {
    const int b    = blockIdx.x;
    const int n    = b / TILES_PER_N;
    const int tile = b - n * TILES_PER_N;
    const int base = n * (C_ * HW_) + tile * TILE_;

    const int t    = threadIdx.x;
    const int q    = t & 15;     // float4 slot -> hw offsets q*4 .. q*4+3
    const int crow = t >> 4;     // 0..15: channel row within each group of 16
    const int w    = t >> 6;     // wave id 0..3

    __shared__ f4 pw[4][16];     // per-wave, per-q partial absmax

    // ---- nontemporal load: all 256 channels for my 4 hw positions ----
    const float* p = in + base + crow * HW_ + q * 4;
    f4 v[16];
    #pragma unroll
    for (int it = 0; it < 16; ++it)
        v[it] = __builtin_nontemporal_load(
                    reinterpret_cast<const f4*>(p + it * (16 * HW_)));

    // ---- per-thread partial absmax over my 16 channel rows ----
    float m0 = 0.f, m1 = 0.f, m2 = 0.f, m3 = 0.f;
    #pragma unroll
    for (int it = 0; it < 16; ++it) {
        m0 = fmaxf(m0, fabsf(v[it].x));
        m1 = fmaxf(m1, fabsf(v[it].y));
        m2 = fmaxf(m2, fabsf(v[it].z));
        m3 = fmaxf(m3, fabsf(v[it].w));
    }

    // ---- wave-internal reduce across the 4 lanes sharing this q (bits 4..5) ----
    #pragma unroll
    for (int mask = 16; mask <= 32; mask <<= 1) {
        m0 = fmaxf(m0, __shfl_xor(m0, mask, 64));
        m1 = fmaxf(m1, __shfl_xor(m1, mask, 64));
        m2 = fmaxf(m2, __shfl_xor(m2, mask, 64));
        m3 = fmaxf(m3, __shfl_xor(m3, mask, 64));
    }
    if (crow == (w << 2)) {      // first lane of each q within the wave
        f4 pv; pv.x = m0; pv.y = m1; pv.z = m2; pv.w = m3;
        pw[w][q] = pv;
    }
    __syncthreads();

    // ---- combine the 4 wave partials (broadcast LDS reads) ----
    const f4 a0 = pw[0][q], a1 = pw[1][q], a2 = pw[2][q], a3 = pw[3][q];
    const float amx = fmaxf(fmaxf(a0.x, a1.x), fmaxf(a2.x, a3.x));
    const float amy = fmaxf(fmaxf(a0.y, a1.y), fmaxf(a2.y, a3.y));
    const float amz = fmaxf(fmaxf(a0.z, a1.z), fmaxf(a2.z, a3.z));
    const float amw = fmaxf(fmaxf(a0.w, a1.w), fmaxf(a2.w, a3.w));

    float u0, r0, u1, r1, u2, r2, u3, r3;
    po2_scales(amx, u0, r0);
    po2_scales(amy, u1, r1);
    po2_scales(amz, u2, r2);
    po2_scales(amw, u3, r3);

    // ---- quantize from registers, nontemporal coalesced store ----
    float* po = out + base + crow * HW_ + q * 4;
    #pragma unroll
    for (int it = 0; it < 16; ++it) {
        f4 o;
        o.x = fminf(fmaxf(rintf(v[it].x * r0), -7.f), 7.f) * u0;
        o.y = fminf(fmaxf(rintf(v[it].y * r1), -7.f), 7.f) * u1;
        o.z = fminf(fmaxf(rintf(v[it].z * r2), -7.f), 7.f) * u2;
        o.w = fminf(fmaxf(rintf(v[it].w * r3), -7.f), 7.f) * u3;
        __builtin_nontemporal_store(o,
            reinterpret_cast<f4*>(po + it * (16 * HW_)));
    }
}

extern "C" void kernel_launch(void* const* d_in, const int* in_sizes, int n_in,
                              void* d_out, int out_size, void* d_ws, size_t ws_size,
                              hipStream_t stream) {
    const float* in = (const float*)d_in[0];
    float* out = (float*)d_out;
    const int grid = N_ * TILES_PER_N;   // 64*49 = 3136 blocks
    bfp_quant_kernel<<<grid, 256, 0, stream>>>(in, out);
}